// Round 5
// baseline (144.213 us; speedup 1.0000x reference)
//
#include <hip/hip_runtime.h>
#include <hip/hip_bf16.h>

#define NB 16384      // rows (B)
#define NC 1000       // classes (C)
#define NV (NC / 4)   // float4 per row = 250
#define NBLK 1024     // persistent-ish grid: 1024 blocks x 4 waves = 4096 waves
#define NW   4096     // total waves; each wave owns 4 rows: w, w+4096, w+8192, w+12288

__global__ __launch_bounds__(256) void ranking_loss_kernel(
        const float* __restrict__ logits,
        const float* __restrict__ target,
        float* __restrict__ partial) {
    const int t    = threadIdx.x;
    const int wave = t >> 6;
    const int lane = t & 63;
    const int w    = blockIdx.x * 4 + wave;   // 0..4095

    const int  i0 = lane;
    const int  i1 = 64 + lane;
    const int  i2 = 128 + lane;
    const int  i3raw = 192 + lane;
    const int  i3 = (i3raw < NV) ? i3raw : (NV - 1);  // clamp -> uniform flow
    const bool v3 = (i3raw < NV);                     // lanes 0..57 valid
    const float inv_pos = 1.0f / (float)(NC - 1);

    // ping-pong register buffers (named float4s -> stay in VGPRs)
    float4 ta0, ta1, ta2, ta3, la0, la1, la2, la3;
    float4 tb0, tb1, tb2, tb3, lb0, lb1, lb2, lb3;

#define LOADR(T0, T1, T2, T3, L0, L1, L2, L3, ROW)                       \
    {                                                                    \
        const float4* t4_ = (const float4*)(target + (size_t)(ROW) * NC);\
        const float4* l4_ = (const float4*)(logits + (size_t)(ROW) * NC);\
        T0 = t4_[i0]; T1 = t4_[i1]; T2 = t4_[i2]; T3 = t4_[i3];          \
        L0 = l4_[i0]; L1 = l4_[i1]; L2 = l4_[i2]; L3 = l4_[i3];          \
    }

#define ARGMAX_F4(V, BASE)                                               \
    {                                                                    \
        const int base_ = (BASE);                                        \
        if (V.x > bv) { bv = V.x; bi = base_ + 0; }                      \
        if (V.y > bv) { bv = V.y; bi = base_ + 1; }                      \
        if (V.z > bv) { bv = V.z; bi = base_ + 2; }                      \
        if (V.w > bv) { bv = V.w; bi = base_ + 3; }                      \
    }

#define HINGE_F4(V, BASE)                                                             \
    {                                                                                 \
        const int base_ = (BASE);                                                     \
        {                                                                             \
            float m0 = (base_ == 0) ? 1.0f : fabsf((float)(label - base_)) * inv_pos; \
            sum += fmaxf(V.x - x1 + m0, 0.0f);                                        \
        }                                                                             \
        sum += fmaxf(V.y - x1 + fabsf((float)(label - (base_ + 1))) * inv_pos, 0.0f); \
        sum += fmaxf(V.z - x1 + fabsf((float)(label - (base_ + 2))) * inv_pos, 0.0f); \
        sum += fmaxf(V.w - x1 + fabsf((float)(label - (base_ + 3))) * inv_pos, 0.0f); \
    }

#define COMPUTE(T0, T1, T2, T3, L0, L1, L2, L3, ROW)                     \
    {                                                                    \
        float bv = -INFINITY;                                            \
        int   bi = NC;                                                   \
        ARGMAX_F4(T0, i0 * 4)                                            \
        ARGMAX_F4(T1, i1 * 4)                                            \
        ARGMAX_F4(T2, i2 * 4)                                            \
        if (v3) ARGMAX_F4(T3, i3 * 4)                                    \
        _Pragma("unroll")                                                \
        for (int off = 1; off < 64; off <<= 1) {                         \
            float ov = __shfl_xor(bv, off, 64);                          \
            int   oi = __shfl_xor(bi, off, 64);                          \
            if (ov > bv || (ov == bv && oi < bi)) { bv = ov; bi = oi; }  \
        }                                                                \
        const int label = bi; /* wave-uniform */                         \
        const int v4_       = label >> 2;                                \
        const int src_lane_ = v4_ & 63;                                  \
        const int chunk_    = v4_ >> 6;                                  \
        const int comp_     = label & 3;                                 \
        float4 f_ = (chunk_ == 0) ? L0 : (chunk_ == 1) ? L1              \
                  : (chunk_ == 2) ? L2 : L3;                             \
        float cand_ = (comp_ == 0) ? f_.x : (comp_ == 1) ? f_.y          \
                    : (comp_ == 2) ? f_.z : f_.w;                        \
        const float x1 = __shfl(cand_, src_lane_, 64);                   \
        float sum = 0.0f;                                                \
        HINGE_F4(L0, i0 * 4)                                             \
        HINGE_F4(L1, i1 * 4)                                             \
        HINGE_F4(L2, i2 * 4)                                             \
        if (v3) HINGE_F4(L3, i3 * 4)                                     \
        _Pragma("unroll")                                                \
        for (int off = 32; off > 0; off >>= 1)                           \
            sum += __shfl_down(sum, off, 64);                            \
        if (lane == 0)                                                   \
            partial[(ROW)] = (label != 0) ? sum * (1.0f / (float)NB)     \
                                          : 0.0f;                        \
    }

    const int r0 = w;
    const int r1 = w + NW;
    const int r2 = w + 2 * NW;
    const int r3 = w + 3 * NW;

    // 2-deep pipeline: loads for the next row are in flight during compute.
    LOADR(ta0, ta1, ta2, ta3, la0, la1, la2, la3, r0)
    LOADR(tb0, tb1, tb2, tb3, lb0, lb1, lb2, lb3, r1)
    COMPUTE(ta0, ta1, ta2, ta3, la0, la1, la2, la3, r0)
    LOADR(ta0, ta1, ta2, ta3, la0, la1, la2, la3, r2)
    COMPUTE(tb0, tb1, tb2, tb3, lb0, lb1, lb2, lb3, r1)
    LOADR(tb0, tb1, tb2, tb3, lb0, lb1, lb2, lb3, r3)
    COMPUTE(ta0, ta1, ta2, ta3, la0, la1, la2, la3, r2)
    COMPUTE(tb0, tb1, tb2, tb3, lb0, lb1, lb2, lb3, r3)

#undef LOADR
#undef ARGMAX_F4
#undef HINGE_F4
#undef COMPUTE
}

// Sum 16384 partials -> out[0]. One block, 256 threads, float4 loads.
__global__ __launch_bounds__(256) void reduce_partials_kernel(
        const float* __restrict__ partial,
        float* __restrict__ out) {
    const int t    = threadIdx.x;
    const int wave = t >> 6;
    const int lane = t & 63;

    float sum = 0.0f;
    const float4* p4 = (const float4*)partial;
    #pragma unroll
    for (int i = 0; i < 16; ++i) {
        float4 v = p4[t + i * 256];
        sum += (v.x + v.y) + (v.z + v.w);
    }
    #pragma unroll
    for (int off = 32; off > 0; off >>= 1)
        sum += __shfl_down(sum, off, 64);

    __shared__ float s_sum[4];
    if (lane == 0) s_sum[wave] = sum;
    __syncthreads();
    if (t == 0)
        out[0] = s_sum[0] + s_sum[1] + s_sum[2] + s_sum[3];
}

extern "C" void kernel_launch(void* const* d_in, const int* in_sizes, int n_in,
                              void* d_out, int out_size, void* d_ws, size_t ws_size,
                              hipStream_t stream) {
    const float* logits = (const float*)d_in[0];
    const float* target = (const float*)d_in[1];
    float* out     = (float*)d_out;
    float* partial = (float*)d_ws;   // NB floats = 64 KB scratch

    ranking_loss_kernel<<<NBLK, 256, 0, stream>>>(logits, target, partial);
    reduce_partials_kernel<<<1, 256, 0, stream>>>(partial, out);
}

// Round 6
// 143.014 us; speedup vs baseline: 1.0084x; 1.0084x over previous
//
#include <hip/hip_runtime.h>
#include <hip/hip_bf16.h>

#define NB 16384      // rows (B)
#define NC 1000       // classes (C)
#define NV 250        // float4 per row
#define NW_B 4096     // kernel-B waves, 4 rows each

// ---------------- Kernel A: wave-per-row argmax(target) + x1 gather ----------
// labx1[row] = { __int_as_float(label), logits[row][label] }
__global__ __launch_bounds__(256) void argmax_kernel(
        const float* __restrict__ target,
        const float* __restrict__ logits,
        float2* __restrict__ labx1) {
    const int t    = threadIdx.x;
    const int wave = t >> 6;
    const int lane = t & 63;
    const int row  = blockIdx.x * 4 + wave;

    const float4* __restrict__ t4 = (const float4*)(target + (size_t)row * NC);
    const int i0 = lane;
    const int i1 = 64 + lane;
    const int i2 = 128 + lane;
    const int i3 = (192 + lane < NV) ? (192 + lane) : (NV - 1);  // clamp; dup keys harmless

    float4 v0 = t4[i0], v1 = t4[i1], v2 = t4[i2], v3 = t4[i3];

    // lane-local argmax, increasing j with strict '>' => first-index tie-break
    float bv = v0.x; int bi = i0 * 4;
#define AM(VAL, IDX) if ((VAL) > bv) { bv = (VAL); bi = (IDX); }
    AM(v0.y, i0*4+1) AM(v0.z, i0*4+2) AM(v0.w, i0*4+3)
    AM(v1.x, i1*4+0) AM(v1.y, i1*4+1) AM(v1.z, i1*4+2) AM(v1.w, i1*4+3)
    AM(v2.x, i2*4+0) AM(v2.y, i2*4+1) AM(v2.z, i2*4+2) AM(v2.w, i2*4+3)
    AM(v3.x, i3*4+0) AM(v3.y, i3*4+1) AM(v3.z, i3*4+2) AM(v3.w, i3*4+3)
#undef AM

    // exact packed key: target >= 0 so float bits are monotonic.
    // high 32 = value bits, low 32 = NC - idx (bigger = smaller idx => ties -> first index)
    unsigned long long key =
        ((unsigned long long)__float_as_uint(bv) << 32) | (unsigned)(NC - bi);
    #pragma unroll
    for (int off = 1; off < 64; off <<= 1) {
        unsigned long long ok = __shfl_xor(key, off, 64);
        key = (ok > key) ? ok : key;
    }
    const int label = NC - (int)(key & 0xFFFFFFFFu);

    if (lane == 0) {
        const float x1 = logits[(size_t)row * NC + label];
        labx1[row] = make_float2(__int_as_float(label), x1);
    }
}

// ---------------- Kernel B: 4 rows per wave, pure streaming hinge sum --------
__global__ __launch_bounds__(256) void loss_kernel(
        const float* __restrict__ logits,
        const float2* __restrict__ labx1,
        float* __restrict__ partial) {
    const int t    = threadIdx.x;
    const int wave = t >> 6;
    const int lane = t & 63;
    const int w    = blockIdx.x * 4 + wave;   // 0..4095
    const int row0 = w * 4;

    const int  i0 = lane;
    const int  i1 = 64 + lane;
    const int  i2 = 128 + lane;
    const int  i3 = (192 + lane < NV) ? (192 + lane) : (NV - 1);
    const bool v3w = (192 + lane) < NV;
    const float inv_pos = 1.0f / (float)(NC - 1);

    // 16 independent streaming loads (issue first)
    const float4* __restrict__ r0 = (const float4*)(logits + (size_t)(row0 + 0) * NC);
    const float4* __restrict__ r1 = (const float4*)(logits + (size_t)(row0 + 1) * NC);
    const float4* __restrict__ r2 = (const float4*)(logits + (size_t)(row0 + 2) * NC);
    const float4* __restrict__ r3 = (const float4*)(logits + (size_t)(row0 + 3) * NC);
    float4 a0 = r0[i0], a1 = r0[i1], a2 = r0[i2], a3 = r0[i3];
    float4 b0 = r1[i0], b1 = r1[i1], b2 = r1[i2], b3 = r1[i3];
    float4 c0 = r2[i0], c1 = r2[i1], c2 = r2[i2], c3 = r2[i3];
    float4 d0 = r3[i0], d1 = r3[i1], d2 = r3[i2], d3 = r3[i3];

    // per-row label/x1 (8B each, wave-uniform broadcast loads)
    const float2 p0 = labx1[row0 + 0];
    const float2 p1 = labx1[row0 + 1];
    const float2 p2 = labx1[row0 + 2];
    const float2 p3 = labx1[row0 + 3];

    float sum = 0.0f;

#define HINGE_F4(V, BASE, LABEL, X1)                                                      \
    {                                                                                     \
        const int base_ = (BASE);                                                         \
        {                                                                                 \
            float m0 = (base_ == 0) ? 1.0f : fabsf((float)((LABEL) - base_)) * inv_pos;   \
            sum += fmaxf(V.x - (X1) + m0, 0.0f);                                          \
        }                                                                                 \
        sum += fmaxf(V.y - (X1) + fabsf((float)((LABEL) - (base_ + 1))) * inv_pos, 0.0f); \
        sum += fmaxf(V.z - (X1) + fabsf((float)((LABEL) - (base_ + 2))) * inv_pos, 0.0f); \
        sum += fmaxf(V.w - (X1) + fabsf((float)((LABEL) - (base_ + 3))) * inv_pos, 0.0f); \
    }

#define HROW(V0, V1, V2, V3, P)                                      \
    {                                                                \
        const int   label = __float_as_int(P.x);                     \
        const float x1    = P.y;                                     \
        if (label != 0) {   /* wave-uniform branch */                \
            HINGE_F4(V0, i0 * 4, label, x1)                          \
            HINGE_F4(V1, i1 * 4, label, x1)                          \
            HINGE_F4(V2, i2 * 4, label, x1)                          \
            if (v3w) HINGE_F4(V3, i3 * 4, label, x1)                 \
        }                                                            \
    }

    HROW(a0, a1, a2, a3, p0)
    HROW(b0, b1, b2, b3, p1)
    HROW(c0, c1, c2, c3, p2)
    HROW(d0, d1, d2, d3, p3)
#undef HROW
#undef HINGE_F4

    // ONE cross-lane reduce per wave lifetime (4 rows amortized)
    #pragma unroll
    for (int off = 32; off > 0; off >>= 1)
        sum += __shfl_down(sum, off, 64);

    if (lane == 0)
        partial[w] = sum * (1.0f / (float)NB);
}

// ---------------- Reduce 4096 partials -> out[0] -----------------------------
__global__ __launch_bounds__(256) void reduce_partials_kernel(
        const float* __restrict__ partial,
        float* __restrict__ out) {
    const int t    = threadIdx.x;
    const int wave = t >> 6;
    const int lane = t & 63;

    float sum = 0.0f;
    const float4* p4 = (const float4*)partial;   // 1024 float4
    #pragma unroll
    for (int i = 0; i < 4; ++i) {
        float4 v = p4[t + i * 256];
        sum += (v.x + v.y) + (v.z + v.w);
    }
    #pragma unroll
    for (int off = 32; off > 0; off >>= 1)
        sum += __shfl_down(sum, off, 64);

    __shared__ float s_sum[4];
    if (lane == 0) s_sum[wave] = sum;
    __syncthreads();
    if (t == 0)
        out[0] = s_sum[0] + s_sum[1] + s_sum[2] + s_sum[3];
}

extern "C" void kernel_launch(void* const* d_in, const int* in_sizes, int n_in,
                              void* d_out, int out_size, void* d_ws, size_t ws_size,
                              hipStream_t stream) {
    const float* logits = (const float*)d_in[0];
    const float* target = (const float*)d_in[1];
    float* out = (float*)d_out;

    float2* labx1   = (float2*)d_ws;                        // 16384 * 8B = 128 KB
    float*  partial = (float*)((char*)d_ws + NB * 8);       // 4096  * 4B = 16 KB

    argmax_kernel<<<NB / 4, 256, 0, stream>>>(target, logits, labx1);
    loss_kernel<<<NW_B / 4, 256, 0, stream>>>(logits, labx1, partial);
    reduce_partials_kernel<<<1, 256, 0, stream>>>(partial, out);
}